// Round 4
// baseline (147.592 us; speedup 1.0000x reference)
//
#include <hip/hip_runtime.h>

#define OD 26
#define OH 122
#define OW 122
#define GS (128*128)
#define NOUT (OD*OH*OW)

// Guide LDS tile for an 8x8x4 voxel block: needs 14 x 14 x 10 floats.
// TLX padded 14 -> 24. The LDS conflict domain is the 32-lane HALF-wave
// (ty 0..3 within a wave); bank start per ty row is (ty*TLX) mod 32.
// TLX=24 gives {0,24,16,8} -> every scalar ds_read_b32 covers all 32 banks
// exactly once. VERIFIED R7: SQ_LDS_BANK_CONFLICT 8.6M -> 0. (TLX=14/20 both
// left 2-lane pileups -> 1.6 cyc/read tax.) 24*14*10 = 3360 fl = 13.44 KB.
#define TLX 24
#define TLY 14
#define TLZ 10
#define TLSLICE (TLX*TLY)      // 336
#define TLN (TLSLICE*TLZ)      // 3360

// Single fused kernel. R8 changes:
//   1. __launch_bounds__ back to plain (256). VERIFIED FAILURES: every
//      min-waves hint spills here — R2/R3 ((64,4)/rolling window: ~800B/thr),
//      R7 ((256,4): allocator clamped to 64 VGPR vs ~85 demand, WRITE_SIZE
//      2.7->14.7MB, 78->118us despite 36% occupancy). Plain bounds is the
//      ONLY spelling the allocator has handled spill-free (R1/R5: 76-88 VGPR).
//   2. dk[27] computed in-block (d0[125] -> dk[27] in LDS, ~60 one-off
//      FMA/thread; dn is 2.9KB, L2-resident). Deletes the serial 1-block
//      compute_dk dispatch + launch boundary: main kernel was ~78us but the
//      bench graph measured ~147us every round — the extra dispatch chain is
//      the only other thing in the graph.
//   3. Keep R7's abs-hoist (VALU-neutral measured, never worse) + TLX=24.
// The asm memory clobber between slices is REQUIRED (blocks cross-slice LDS
// CSE that would rebuild the full-tile live range — R3's failure mode).
__global__ __launch_bounds__(256) void jbf_main_kernel(
        const float* __restrict__ x, const float* __restrict__ guide,
        const float* __restrict__ dn,
        const float* __restrict__ rw0p, const float* __restrict__ rb0p,
        const float* __restrict__ rw1p, const float* __restrict__ rb1p,
        const float* __restrict__ dw0, const float* __restrict__ db0,
        const float* __restrict__ dw1, const float* __restrict__ db1,
        float* __restrict__ out) {
    __shared__ float gl[TLN];
    __shared__ float d0s[125];
    __shared__ float dks[27];

    const int xb = blockIdx.x * 8;
    const int yb = blockIdx.y * 8;
    const int zb = blockIdx.z * 4;

    // Cooperative guide staging, coords clamped (edge tiles read dup rows;
    // in-range voxels only consume in-bounds neighbors, so values are exact.
    // Pad columns gx>=14 are never read; clamped loads keep them in-bounds).
    for (int i = threadIdx.x; i < TLN; i += 256) {
        const int gx = i % TLX;
        const int gy = (i / TLX) % TLY;
        const int gz = i / TLSLICE;
        const int sx = min(xb + gx, 127);
        const int sy = min(yb + gy, 127);
        const int sz = min(zb + gz, 31);
        gl[i] = guide[sz*GS + sy*128 + sx];
    }

    // Domain-kernel stage 1 (redundant per block, one-off, overlaps staging):
    // d0[5^3] = relu(conv3d(dn[1:8,1:8,1:8], dw0) + db0).
    {
        const int t = threadIdx.x;
        if (t < 125) {
            const int tz = t / 25, ty = (t / 5) % 5, tx = t % 5;
            float acc = db0[0];
            #pragma unroll
            for (int kz = 0; kz < 3; ++kz)
                #pragma unroll
                for (int ky = 0; ky < 3; ++ky)
                    #pragma unroll
                    for (int kx = 0; kx < 3; ++kx)
                        acc += dw0[kz*9 + ky*3 + kx] *
                               dn[(1+tz+kz)*81 + (1+ty+ky)*9 + (1+tx+kx)];
            d0s[t] = fmaxf(acc, 0.0f);
        }
    }
    __syncthreads();

    // Domain-kernel stage 2: dk[3^3] = relu(conv3d(d0, dw1) + db1).
    if (threadIdx.x < 27) {
        const int t = threadIdx.x;
        const int rz = t / 9, ry = (t / 3) % 3, rx = t % 3;
        float acc = db1[0];
        #pragma unroll
        for (int kz = 0; kz < 3; ++kz)
            #pragma unroll
            for (int ky = 0; ky < 3; ++ky)
                #pragma unroll
                for (int kx = 0; kx < 3; ++kx)
                    acc += dw1[kz*9 + ky*3 + kx] * d0s[(rz+kz)*25 + (ry+ky)*5 + (rx+kx)];
        dks[t] = fmaxf(acc, 0.0f);
    }
    __syncthreads();

    const int tx = threadIdx.x & 7;
    const int ty = (threadIdx.x >> 3) & 7;
    const int tz = threadIdx.x >> 6;
    const int x0 = xb + tx;
    const int y0 = yb + ty;
    const int z0 = zb + tz;
    if (x0 >= OW || y0 >= OH || z0 >= OD) return;

    // Wave-uniform weights -> SGPRs (uniform loads; survive the clobbers as
    // SSA values — only LDS reads are re-issued per slice).
    float rw0[27], rw1[27];
    #pragma unroll
    for (int i = 0; i < 27; ++i) { rw0[i] = rw0p[i]; rw1[i] = rw1p[i]; }
    const float rb0 = rb0p[0], rb1 = rb1p[0];

    // Per-thread LDS base: all inner reads are base + compile-time offset.
    const float* glb = &gl[tz*TLSLICE + ty*TLX + tx];
    const float gc = glb[3*TLSLICE + 3*TLX + 3];

    // conv2 accumulators (bias added once here; slice contributions add in).
    float rk[27];
    #pragma unroll
    for (int i = 0; i < 27; ++i) rk[i] = rb1;

    #pragma unroll
    for (int tz1 = 0; tz1 < 5; ++tz1) {
        // conv1, z-slice tz1: t0s(ty1,txx) = relu(rb0 + sum_k rw0(k)*a)
        float t0s[25];
        #pragma unroll
        for (int i = 0; i < 25; ++i) t0s[i] = rb0;

        #pragma unroll
        for (int kz = 0; kz < 3; ++kz) {
            const int gz = tz1 + kz;
            #pragma unroll
            for (int gy = 0; gy < 7; ++gy) {
                // Row abs-diffs computed ONCE; FMAs consume clean positives.
                float a[7];
                #pragma unroll
                for (int j = 0; j < 7; ++j)
                    a[j] = fabsf(glb[gz*TLSLICE + gy*TLX + j] - gc);
                #pragma unroll
                for (int ky = 0; ky < 3; ++ky) {
                    const int ty1 = gy - ky;
                    if (ty1 < 0 || ty1 > 4) continue;          // folds at compile time
                    #pragma unroll
                    for (int txx = 0; txx < 5; ++txx)
                        #pragma unroll
                        for (int kx = 0; kx < 3; ++kx)
                            t0s[ty1*5 + txx] =
                                fmaf(rw0[kz*9 + ky*3 + kx], a[txx + kx],
                                     t0s[ty1*5 + txx]);
                }
            }
        }
        #pragma unroll
        for (int i = 0; i < 25; ++i) t0s[i] = fmaxf(t0s[i], 0.0f);

        // Drain slice into conv2 accumulators: rk(rz,·,·) gets the kz2 = tz1-rz tap.
        #pragma unroll
        for (int kz2 = 0; kz2 < 3; ++kz2) {
            const int rz = tz1 - kz2;
            if (rz < 0 || rz > 2) continue;                    // folds at compile time
            #pragma unroll
            for (int ry = 0; ry < 3; ++ry)
                #pragma unroll
                for (int rx = 0; rx < 3; ++rx) {
                    #pragma unroll
                    for (int ky2 = 0; ky2 < 3; ++ky2)
                        #pragma unroll
                        for (int kx2 = 0; kx2 < 3; ++kx2)
                            rk[rz*9 + ry*3 + rx] =
                                fmaf(rw1[kz2*9 + ky2*3 + kx2],
                                     t0s[(ry+ky2)*5 + (rx+kx2)],
                                     rk[rz*9 + ry*3 + rx]);
                }
        }

        // Block LDS-load CSE across slices — keeps per-slice pressure bounded.
        asm volatile("" ::: "memory");
    }

    // Epilogue: relu(rk) * dk weighting + normalized reduction.
    // dks reads are wave-uniform LDS addresses -> broadcast, conflict-free.
    float num = 0.0f, den = 0.0f;
    const float* xbp = x + (z0+2)*GS + (y0+2)*128 + (x0+2);
    #pragma unroll
    for (int rz = 0; rz < 3; ++rz)
        #pragma unroll
        for (int ry = 0; ry < 3; ++ry)
            #pragma unroll
            for (int rx = 0; rx < 3; ++rx) {
                const float w = dks[rz*9 + ry*3 + rx]
                              * fmaxf(rk[rz*9 + ry*3 + rx], 0.0f) + 1e-10f;
                den += w;
                num = fmaf(w, xbp[rz*GS + ry*128 + rx], num);
            }

    out[(z0*OH + y0)*OW + x0] = num / den;
}

extern "C" void kernel_launch(void* const* d_in, const int* in_sizes, int n_in,
                              void* d_out, int out_size, void* d_ws, size_t ws_size,
                              hipStream_t stream) {
    const float* x     = (const float*)d_in[0];
    const float* dn    = (const float*)d_in[1];
    const float* guide = (const float*)d_in[2];
    const float* rw0   = (const float*)d_in[3];
    const float* rb0   = (const float*)d_in[4];
    const float* rw1   = (const float*)d_in[5];
    const float* rb1   = (const float*)d_in[6];
    const float* dw0   = (const float*)d_in[7];
    const float* db0   = (const float*)d_in[8];
    const float* dw1   = (const float*)d_in[9];
    const float* db1   = (const float*)d_in[10];
    float* out = (float*)d_out;

    dim3 grid((OW + 7) / 8, (OH + 7) / 8, (OD + 3) / 4);   // 16 x 16 x 7
    jbf_main_kernel<<<grid, 256, 0, stream>>>(x, guide, dn,
                                              rw0, rb0, rw1, rb1,
                                              dw0, db0, dw1, db1, out);
}